// Round 10
// baseline (363.050 us; speedup 1.0000x reference)
//
#include <hip/hip_runtime.h>
#include <hip/hip_bf16.h>

// ---------------- problem constants ----------------
constexpr int NN = 100000;   // nodes
constexpr int NE = 1600000;  // directed edges
constexpr int BKN  = 256;                  // nodes per bucket
constexpr int NB2  = (NN + BKN - 1) / BKN; // 391 buckets
constexpr int TILE = 4096;                 // edges per scatter block
constexpr int NT   = (NE + TILE - 1) / TILE; // 391 tiles

// ---------------- bf16 / fp8 helpers ----------------
__device__ __forceinline__ unsigned short f2bf(float f) {
    unsigned int u = __float_as_uint(f);
    unsigned int r = (u + 0x7fffu + ((u >> 16) & 1u)) >> 16;
    return (unsigned short)r;
}
__device__ __forceinline__ float bflo(unsigned int u) { return __uint_as_float(u << 16); }
__device__ __forceinline__ float bfhi(unsigned int u) { return __uint_as_float(u & 0xffff0000u); }
__device__ __forceinline__ float bf2f(unsigned short h) { return __uint_as_float(((unsigned int)h) << 16); }
__device__ __forceinline__ unsigned int pack2bf(float lo, float hi) {
    return (unsigned int)f2bf(lo) | ((unsigned int)f2bf(hi) << 16);
}

typedef __bf16 v8bf __attribute__((ext_vector_type(8)));
typedef float  v4f  __attribute__((ext_vector_type(4)));
typedef float  v2f  __attribute__((ext_vector_type(2)));

__device__ __forceinline__ v2f fp8lo(unsigned int u) {
    return __builtin_amdgcn_cvt_pk_f32_fp8(u, false);   // bytes 0,1
}
__device__ __forceinline__ v2f fp8hi(unsigned int u) {
    return __builtin_amdgcn_cvt_pk_f32_fp8(u, true);    // bytes 2,3
}

// ---------------- workspace layout (bytes) ----------------
constexpr size_t OFF_BCNT  = 0;                          // NB2+1 ints
constexpr size_t OFF_BBASE = OFF_BCNT  + 2048;           // NB2+1 ints
constexpr size_t OFF_BCUR  = OFF_BBASE + 2048;           // NB2 ints
constexpr size_t OFF_RP    = OFF_BCUR  + 2048;           // NN+1 ints
constexpr size_t OFF_DINV  = OFF_RP    + 400384;         // NN floats
constexpr size_t OFF_COL   = OFF_DINV  + 400384;         // E ints
constexpr size_t OFF_WT    = OFF_COL   + 6400000;        // 128x128 bf16 (W^T per layer)
constexpr size_t OFF_H8    = OFF_WT    + 32768;          // N*128 fp8 (mid-layer messages, prescaled)
constexpr size_t OFF_H     = OFF_H8    + 12800000;       // N*128 bf16 (layer-4 messages; ebuf alias in preproc)
constexpr size_t OFF_X     = OFF_H     + 25600000;       // N*128 bf16 (residual spine)
// ebuf (E uint = 6.4 MB) aliases OFF_H (dead until layer-4 GEMM)

// ---------------- preprocessing: radix-partition CSR build ----------------

__global__ __launch_bounds__(256) void bhist_kernel(const int* __restrict__ edst,
                                                    int* __restrict__ bcnt) {
    __shared__ int h[NB2];
    for (int i = threadIdx.x; i < NB2; i += 256) h[i] = 0;
    __syncthreads();
    const int base = blockIdx.x * TILE;
    #pragma unroll
    for (int j = 0; j < 16; ++j) {
        int e = base + j * 256 + threadIdx.x;
        if (e < NE) atomicAdd(&h[edst[e] >> 8], 1);
    }
    __syncthreads();
    for (int i = threadIdx.x; i < NB2; i += 256)
        if (h[i]) atomicAdd(&bcnt[i], h[i]);
}

__global__ __launch_bounds__(512) void bscan_kernel(const int* __restrict__ bcnt,
                                                    int* __restrict__ bbase,
                                                    int* __restrict__ bcur) {
    __shared__ int s[512];
    const int t = threadIdx.x;
    int v = (t < NB2) ? bcnt[t] : 0;
    s[t] = v;
    __syncthreads();
    for (int off = 1; off < 512; off <<= 1) {
        int a = (t >= off) ? s[t - off] : 0;
        __syncthreads();
        s[t] += a;
        __syncthreads();
    }
    int excl = s[t] - v;
    if (t < NB2) { bbase[t] = excl; bcur[t] = excl; }
    if (t == NB2 - 1) bbase[NB2] = excl + v;   // == NE
}

// edges -> bucket-ordered packed ebuf: src | (dst&255)<<24  (src < 2^17)
__global__ __launch_bounds__(256) void scatter2_kernel(const int* __restrict__ esrc,
                                                       const int* __restrict__ edst,
                                                       int* __restrict__ bcur,
                                                       unsigned int* __restrict__ ebuf) {
    __shared__ int h[NB2];
    __shared__ int cur[NB2];
    for (int i = threadIdx.x; i < NB2; i += 256) h[i] = 0;
    __syncthreads();
    const int base = blockIdx.x * TILE;
    #pragma unroll
    for (int j = 0; j < 16; ++j) {
        int e = base + j * 256 + threadIdx.x;
        if (e < NE) atomicAdd(&h[edst[e] >> 8], 1);
    }
    __syncthreads();
    for (int i = threadIdx.x; i < NB2; i += 256) {
        int c = h[i];
        cur[i] = c ? atomicAdd(&bcur[i], c) : 0;
    }
    __syncthreads();
    #pragma unroll
    for (int j = 0; j < 16; ++j) {
        int e = base + j * 256 + threadIdx.x;
        if (e < NE) {
            int s = esrc[e], d = edst[e];
            int pos = atomicAdd(&cur[d >> 8], 1);
            ebuf[pos] = (unsigned int)s | ((unsigned int)(d & 255) << 24);
        }
    }
}

__global__ __launch_bounds__(256) void csrfill2_kernel(const unsigned int* __restrict__ ebuf,
                                                       const int* __restrict__ bbase,
                                                       int* __restrict__ rp,
                                                       float* __restrict__ dinv,
                                                       int* __restrict__ col) {
    __shared__ int cnt[256];
    __shared__ int cursor[256];
    __shared__ int s[256];
    __shared__ int sbeg, send;
    const int b = blockIdx.x;
    const int t = threadIdx.x;
    if (t == 0) { sbeg = bbase[b]; send = bbase[b + 1]; }
    cnt[t] = 0;
    __syncthreads();
    const int beg = sbeg, end = send;
    const int node0 = b * BKN;

    for (int e = beg + t; e < end; e += 256)
        atomicAdd(&cnt[ebuf[e] >> 24], 1);
    __syncthreads();

    int v = cnt[t];
    s[t] = v;
    __syncthreads();
    for (int off = 1; off < 256; off <<= 1) {
        int a = (t >= off) ? s[t - off] : 0;
        __syncthreads();
        s[t] += a;
        __syncthreads();
    }
    int excl = s[t] - v;
    int gnode = node0 + t;
    if (gnode < NN) {
        rp[gnode]   = beg + excl;
        dinv[gnode] = rsqrtf((float)(v + 1));   // +1 self loop
    }
    cursor[t] = beg + excl;
    if (b == NB2 - 1 && t == 0) rp[NN] = NE;
    __syncthreads();

    for (int e = beg + t; e < end; e += 256) {
        unsigned int sd = ebuf[e];
        int pos = atomicAdd(&cursor[sd >> 24], 1);
        col[pos] = (int)(sd & 0xFFFFFFu);
    }
}

// ---------------- W pre-transpose: Wt[c][k] = bf16(W[k][c]),  c<64 from W0, c>=64 from W1 ----
__global__ __launch_bounds__(256) void wpre_kernel(const float* __restrict__ W0,
                                                   const float* __restrict__ W1,
                                                   int wstride,
                                                   unsigned short* __restrict__ Wt) {
    int e = blockIdx.x * 256 + threadIdx.x;   // grid 64 -> 16384
    int k = e >> 7, c = e & 127;
    float v = (c < 64) ? W0[(size_t)k * wstride + c] : W1[(size_t)k * wstride + (c - 64)];
    Wt[c * 128 + k] = f2bf(v);
}

// ---------------- MFMA GEMM:  H[n][:] = enc( (X[n][:] @ W) * rowScale ) ----------------
// XF32: X fp32 (layer-1 input) vs bf16 spine.  OUT8: fp8 e4m3 output (mid layers) vs bf16.
constexpr int XROW = 136;   // padded shorts per LDS row

template<bool XF32, bool OUT8>
__global__ __launch_bounds__(256) void gemm_mfma_kernel(const void* __restrict__ Xv,
                                                        const unsigned short* __restrict__ Wt,
                                                        const float* __restrict__ dinv,
                                                        int scaleMask,
                                                        void* __restrict__ Ho) {
    __shared__ unsigned short Wl[128 * XROW];   // W^T staged: [col][k]
    __shared__ unsigned short Xl[64 * XROW];    // X tile bf16; reused for output staging

    const int t = threadIdx.x;
    const int rowBase = blockIdx.x * 64;

    // stage Wt -> LDS: 128 rows x 16 chunks (16B)
    #pragma unroll
    for (int i = 0; i < 8; ++i) {
        int f = i * 256 + t;
        int r = f >> 4, c8 = f & 15;
        uint4 w = *(const uint4*)&Wt[r * 128 + c8 * 8];
        *(uint4*)&Wl[r * XROW + c8 * 8] = w;
    }
    // stage X tile -> LDS bf16
    if (XF32) {
        const float* X = (const float*)Xv;
        #pragma unroll
        for (int i = 0; i < 8; ++i) {
            int f = i * 256 + t;                  // 64 rows x 32 float4
            int r = f >> 5, c4 = f & 31;
            int gn = rowBase + r;
            float4 v = make_float4(0.f, 0.f, 0.f, 0.f);
            if (gn < NN) v = *(const float4*)&X[(size_t)gn * 128 + c4 * 4];
            ushort4 o;
            o.x = f2bf(v.x); o.y = f2bf(v.y); o.z = f2bf(v.z); o.w = f2bf(v.w);
            *(ushort4*)&Xl[r * XROW + c4 * 4] = o;
        }
    } else {
        const unsigned short* X = (const unsigned short*)Xv;
        #pragma unroll
        for (int i = 0; i < 4; ++i) {
            int f = i * 256 + t;                  // 64 rows x 16 uint4 chunks
            int r = f >> 4, c8 = f & 15;
            int gn = rowBase + r;
            uint4 v = make_uint4(0u, 0u, 0u, 0u);
            if (gn < NN) v = *(const uint4*)&X[(size_t)gn * 128 + c8 * 8];
            *(uint4*)&Xl[r * XROW + c8 * 8] = v;
        }
    }
    __syncthreads();

    const int w  = t >> 6;        // wave id: rows w*16 .. w*16+15
    const int l  = t & 63;
    const int lr = l & 15;        // A row / B col within 16
    const int lk = (l >> 4) * 8;  // k sub-offset within each 32-k step

    v4f acc[8];
    #pragma unroll
    for (int n = 0; n < 8; ++n) acc[n] = (v4f){0.f, 0.f, 0.f, 0.f};

    const unsigned short* ax = &Xl[(w * 16 + lr) * XROW + lk];
    const unsigned short* bx = &Wl[lr * XROW + lk];

    #pragma unroll
    for (int kk = 0; kk < 4; ++kk) {
        v8bf a = *(const v8bf*)&ax[kk * 32];
        #pragma unroll
        for (int n = 0; n < 8; ++n) {
            v8bf b = *(const v8bf*)&bx[(n * 16) * XROW + kk * 32];
            acc[n] = __builtin_amdgcn_mfma_f32_16x16x32_bf16(a, b, acc[n], 0, 0, 0);
        }
    }

    // epilogue: scale rows, pack bf16 into LDS (D: col=l&15, row=(l>>4)*4+reg)
    #pragma unroll
    for (int r_ = 0; r_ < 4; ++r_) {
        int row  = w * 16 + (l >> 4) * 4 + r_;
        int grow = rowBase + row;
        float dsc = dinv[grow < NN ? grow : NN - 1];
        #pragma unroll
        for (int n = 0; n < 8; ++n) {
            float sc = ((scaleMask >> (n >> 2)) & 1) ? dsc : 1.f;
            Xl[row * XROW + n * 16 + lr] = f2bf(acc[n][r_] * sc);
        }
    }
    __syncthreads();

    // coalesced store: 64 rows x 16 chunks
    if (OUT8) {
        unsigned char* H8 = (unsigned char*)Ho;
        #pragma unroll
        for (int i = 0; i < 4; ++i) {
            int f = i * 256 + t;
            int r = f >> 4, c8 = f & 15;
            int gn = rowBase + r;
            if (gn < NN) {
                uint4 v = *(const uint4*)&Xl[r * XROW + c8 * 8];
                unsigned int lo = __builtin_amdgcn_cvt_pk_fp8_f32(bflo(v.x), bfhi(v.x), 0u, false);
                lo = __builtin_amdgcn_cvt_pk_fp8_f32(bflo(v.y), bfhi(v.y), lo, true);
                unsigned int hi = __builtin_amdgcn_cvt_pk_fp8_f32(bflo(v.z), bfhi(v.z), 0u, false);
                hi = __builtin_amdgcn_cvt_pk_fp8_f32(bflo(v.w), bfhi(v.w), hi, true);
                *(uint2*)&H8[(size_t)gn * 128 + c8 * 8] = make_uint2(lo, hi);
            }
        }
    } else {
        unsigned short* Hb = (unsigned short*)Ho;
        #pragma unroll
        for (int i = 0; i < 4; ++i) {
            int f = i * 256 + t;
            int r = f >> 4, c8 = f & 15;
            int gn = rowBase + r;
            if (gn < NN) {
                uint4 v = *(const uint4*)&Xl[r * XROW + c8 * 8];
                *(uint4*)&Hb[(size_t)gn * 128 + c8 * 8] = v;
            }
        }
    }
}

// ---------------- aggregation: 128-feature layers, 2 edges per gather instruction ----------------
// Lane L: uint (L&31) of the row of edge e+(L>>5). One VMEM instr = 2 fp8 rows (256B).
// Self term rides in the first pair's upper half slot (lower half handles self).
template<bool XF32>
__global__ __launch_bounds__(256) void agg128_kernel(const unsigned char* __restrict__ H8,
                                                     const void* __restrict__ Xoldv,
                                                     const int* __restrict__ rp,
                                                     const int* __restrict__ col,
                                                     const float* __restrict__ dinv,
                                                     const float* __restrict__ bias,
                                                     uint2* __restrict__ Xnew) {
    const int wid  = threadIdx.x >> 6;
    const int lane = threadIdx.x & 63;
    const int i = blockIdx.x * 4 + wid;
    if (i >= NN) return;
    const int hh = lane >> 5;     // which edge of the pair this half-wave handles
    const int fl = lane & 31;     // uint index within 128B fp8 row (4 features)

    const unsigned int* __restrict__ H32 = (const unsigned int*)H8;

    const float di = dinv[i];
    const float4 b4 = ((const float4*)bias)[fl];
    float4 xo4;
    if (XF32) {
        xo4 = ((const float4*)Xoldv)[(size_t)i * 32 + fl];
    } else {
        uint2 xo = ((const uint2*)Xoldv)[(size_t)i * 32 + fl];
        xo4 = make_float4(bflo(xo.x), bfhi(xo.x), bflo(xo.y), bfhi(xo.y));
    }

    v2f a01 = {0.f, 0.f}, a23 = {0.f, 0.f};

    const int beg = rp[i], end = rp[i + 1];
    // pair 0: (self, first edge)
    {
        int s = i;
        if (hh && beg < end) s = col[beg];
        unsigned int u = H32[(size_t)s * 32 + fl];
        if (!hh || beg < end) { a01 += fp8lo(u); a23 += fp8hi(u); }
    }
    int e = beg + 1;
    for (; e + 8 <= end; e += 8) {
        int s0 = col[e     + hh];
        int s1 = col[e + 2 + hh];
        int s2 = col[e + 4 + hh];
        int s3 = col[e + 6 + hh];
        unsigned int u0 = H32[(size_t)s0 * 32 + fl];
        unsigned int u1 = H32[(size_t)s1 * 32 + fl];
        unsigned int u2 = H32[(size_t)s2 * 32 + fl];
        unsigned int u3 = H32[(size_t)s3 * 32 + fl];
        a01 += (fp8lo(u0) + fp8lo(u1)) + (fp8lo(u2) + fp8lo(u3));
        a23 += (fp8hi(u0) + fp8hi(u1)) + (fp8hi(u2) + fp8hi(u3));
    }
    for (; e + 2 <= end; e += 2) {
        int s = col[e + hh];
        unsigned int u = H32[(size_t)s * 32 + fl];
        a01 += fp8lo(u); a23 += fp8hi(u);
    }
    if (e < end) {                      // odd tail: only lower half contributes
        int s = col[e];
        unsigned int u = H32[(size_t)s * 32 + fl];
        if (!hh) { a01 += fp8lo(u); a23 += fp8hi(u); }
    }

    // merge half-wave partials
    float f0 = a01.x + __shfl_xor(a01.x, 32);
    float f1 = a01.y + __shfl_xor(a01.y, 32);
    float f2 = a23.x + __shfl_xor(a23.x, 32);
    float f3 = a23.y + __shfl_xor(a23.y, 32);

    if (!hh) {
        float o0 = fmaxf(di * f0 + b4.x + xo4.x, 0.f);
        float o1 = fmaxf(di * f1 + b4.y + xo4.y, 0.f);
        float o2 = fmaxf(di * f2 + b4.z + xo4.z, 0.f);
        float o3 = fmaxf(di * f3 + b4.w + xo4.w, 0.f);
        Xnew[(size_t)i * 32 + fl] = make_uint2(pack2bf(o0, o1), pack2bf(o2, o3));
    }
}

// ---------------- final layer: 64-feature conv + bias + skip, 2 edges per gather ----------------
// Hb rows: 64 uints; conv half = uints 0..31, skip = 32..63.
__global__ __launch_bounds__(256) void aggout_kernel(const unsigned short* __restrict__ Hb,
                                                     const int* __restrict__ rp,
                                                     const int* __restrict__ col,
                                                     const float* __restrict__ dinv,
                                                     const float* __restrict__ bias,
                                                     float* __restrict__ out) {
    const int wid  = threadIdx.x >> 6;
    const int lane = threadIdx.x & 63;
    const int i = blockIdx.x * 4 + wid;
    if (i >= NN) return;
    const int hh = lane >> 5;
    const int fl = lane & 31;     // uint index (2 bf16 features)

    const unsigned int* __restrict__ Hu = (const unsigned int*)Hb;

    const float di = dinv[i];
    const float2 b2 = ((const float2*)bias)[fl];
    unsigned int usk = Hu[(size_t)i * 64 + 32 + fl];
    const float sk0 = bflo(usk), sk1 = bfhi(usk);

    float a0 = 0.f, a1 = 0.f;
    const int beg = rp[i], end = rp[i + 1];
    // pair 0: (self, first edge)
    {
        int s = i;
        if (hh && beg < end) s = col[beg];
        unsigned int u = Hu[(size_t)s * 64 + fl];
        if (!hh || beg < end) { a0 += bflo(u); a1 += bfhi(u); }
    }
    int e = beg + 1;
    for (; e + 8 <= end; e += 8) {
        int s0 = col[e     + hh];
        int s1 = col[e + 2 + hh];
        int s2 = col[e + 4 + hh];
        int s3 = col[e + 6 + hh];
        unsigned int u0 = Hu[(size_t)s0 * 64 + fl];
        unsigned int u1 = Hu[(size_t)s1 * 64 + fl];
        unsigned int u2 = Hu[(size_t)s2 * 64 + fl];
        unsigned int u3 = Hu[(size_t)s3 * 64 + fl];
        a0 += (bflo(u0) + bflo(u1)) + (bflo(u2) + bflo(u3));
        a1 += (bfhi(u0) + bfhi(u1)) + (bfhi(u2) + bfhi(u3));
    }
    for (; e + 2 <= end; e += 2) {
        int s = col[e + hh];
        unsigned int u = Hu[(size_t)s * 64 + fl];
        a0 += bflo(u); a1 += bfhi(u);
    }
    if (e < end) {
        int s = col[e];
        unsigned int u = Hu[(size_t)s * 64 + fl];
        if (!hh) { a0 += bflo(u); a1 += bfhi(u); }
    }

    float f0 = a0 + __shfl_xor(a0, 32);
    float f1 = a1 + __shfl_xor(a1, 32);

    if (!hh) {
        ((float2*)out)[(size_t)i * 32 + fl] =
            make_float2(di * f0 + b2.x + sk0, di * f1 + b2.y + sk1);
    }
}

// ---------------- launch ----------------
extern "C" void kernel_launch(void* const* d_in, const int* in_sizes, int n_in,
                              void* d_out, int out_size, void* d_ws, size_t ws_size,
                              hipStream_t stream) {
    const float* x      = (const float*)d_in[0];
    const int*   ei     = (const int*)d_in[1];
    const float* W_in   = (const float*)d_in[2];
    const float* b_in   = (const float*)d_in[3];
    const float* W_mid0 = (const float*)d_in[4];
    const float* b_mid0 = (const float*)d_in[5];
    const float* W_mid1 = (const float*)d_in[6];
    const float* b_mid1 = (const float*)d_in[7];
    const float* W_out  = (const float*)d_in[8];
    const float* b_out  = (const float*)d_in[9];
    const float* W_skip = (const float*)d_in[10];

    const int* esrc = ei;        // edge_index[0]
    const int* edst = ei + NE;   // edge_index[1]

    char* ws = (char*)d_ws;
    int*   bcnt   = (int*)  (ws + OFF_BCNT);
    int*   bbase  = (int*)  (ws + OFF_BBASE);
    int*   bcur   = (int*)  (ws + OFF_BCUR);
    int*   rp     = (int*)  (ws + OFF_RP);
    float* dinv   = (float*)(ws + OFF_DINV);
    int*   col    = (int*)  (ws + OFF_COL);
    unsigned short* wt   = (unsigned short*)(ws + OFF_WT);
    unsigned char*  h8   = (unsigned char*) (ws + OFF_H8);
    unsigned short* hbuf = (unsigned short*)(ws + OFF_H);
    unsigned int*   ebuf = (unsigned int*)  (ws + OFF_H);   // alias: dead before layer-4 GEMM
    unsigned short* xbuf = (unsigned short*)(ws + OFF_X);
    uint2*          xbuf2 = (uint2*)        (ws + OFF_X);
    float* outp   = (float*)d_out;

    const int gemmGrid = (NN + 63) / 64;             // 1563
    const int aggGrid  = (NN + 3) / 4;               // 25000

    // ---- graph preprocessing ----
    hipMemsetAsync(bcnt, 0, (size_t)(NB2 + 1) * 4, stream);
    bhist_kernel<<<NT, 256, 0, stream>>>(edst, bcnt);
    bscan_kernel<<<1, 512, 0, stream>>>(bcnt, bbase, bcur);
    scatter2_kernel<<<NT, 256, 0, stream>>>(esrc, edst, bcur, ebuf);
    csrfill2_kernel<<<NB2, 256, 0, stream>>>(ebuf, bbase, rp, dinv, col);

    // ---- layer 1 (reads fp32 x; fp8 messages; bf16 spine out) ----
    wpre_kernel<<<64, 256, 0, stream>>>(W_in, W_in + 64, 128, wt);
    gemm_mfma_kernel<true, true><<<gemmGrid, 256, 0, stream>>>(x, wt, dinv, 3, h8);
    agg128_kernel<true><<<aggGrid, 256, 0, stream>>>(h8, x, rp, col, dinv, b_in, xbuf2);

    // ---- layer 2 ----
    wpre_kernel<<<64, 256, 0, stream>>>(W_mid0, W_mid0 + 64, 128, wt);
    gemm_mfma_kernel<false, true><<<gemmGrid, 256, 0, stream>>>(xbuf, wt, dinv, 3, h8);
    agg128_kernel<false><<<aggGrid, 256, 0, stream>>>(h8, xbuf, rp, col, dinv, b_mid0, xbuf2);

    // ---- layer 3 ----
    wpre_kernel<<<64, 256, 0, stream>>>(W_mid1, W_mid1 + 64, 128, wt);
    gemm_mfma_kernel<false, true><<<gemmGrid, 256, 0, stream>>>(xbuf, wt, dinv, 3, h8);
    agg128_kernel<false><<<aggGrid, 256, 0, stream>>>(h8, xbuf, rp, col, dinv, b_mid1, xbuf2);

    // ---- layer 4: fused [W_out | W_skip_out] GEMM (bf16 messages; scale only W_out half) ----
    wpre_kernel<<<64, 256, 0, stream>>>(W_out, W_skip, 64, wt);
    gemm_mfma_kernel<false, false><<<gemmGrid, 256, 0, stream>>>(xbuf, wt, dinv, 1, hbuf);
    aggout_kernel<<<aggGrid, 256, 0, stream>>>(hbuf, rp, col, dinv, b_out, outp);
}

// Round 12
// 340.152 us; speedup vs baseline: 1.0673x; 1.0673x over previous
//
#include <hip/hip_runtime.h>
#include <hip/hip_bf16.h>

// ---------------- problem constants ----------------
constexpr int NN = 100000;   // nodes
constexpr int NE = 1600000;  // directed edges
constexpr int BKN  = 256;                  // nodes per bucket
constexpr int NB2  = (NN + BKN - 1) / BKN; // 391 buckets
constexpr int TILE = 4096;                 // edges per scatter block
constexpr int NT   = (NE + TILE - 1) / TILE; // 391 tiles

// ---------------- bf16 / fp8 helpers ----------------
__device__ __forceinline__ unsigned short f2bf(float f) {
    unsigned int u = __float_as_uint(f);
    unsigned int r = (u + 0x7fffu + ((u >> 16) & 1u)) >> 16;
    return (unsigned short)r;
}
__device__ __forceinline__ float bflo(unsigned int u) { return __uint_as_float(u << 16); }
__device__ __forceinline__ float bfhi(unsigned int u) { return __uint_as_float(u & 0xffff0000u); }
__device__ __forceinline__ float bf2f(unsigned short h) { return __uint_as_float(((unsigned int)h) << 16); }
__device__ __forceinline__ unsigned int pack2bf(float lo, float hi) {
    return (unsigned int)f2bf(lo) | ((unsigned int)f2bf(hi) << 16);
}

typedef __bf16 v8bf __attribute__((ext_vector_type(8)));
typedef float  v4f  __attribute__((ext_vector_type(4)));
typedef float  v2f  __attribute__((ext_vector_type(2)));

__device__ __forceinline__ v2f fp8x2_to_f32(unsigned int u) {
    v2f t = __builtin_amdgcn_cvt_pk_f32_fp8(u, false);   // bytes 0,1 -> {x,y}
    return t;
}
__device__ __forceinline__ float fp8b(unsigned char b) {
    v2f t = __builtin_amdgcn_cvt_pk_f32_fp8((unsigned int)b, false);
    return t.x;
}

// ---------------- workspace layout (bytes) ----------------
constexpr size_t OFF_BCNT  = 0;                          // NB2+1 ints
constexpr size_t OFF_BBASE = OFF_BCNT  + 2048;           // NB2+1 ints
constexpr size_t OFF_BCUR  = OFF_BBASE + 2048;           // NB2 ints
constexpr size_t OFF_RP    = OFF_BCUR  + 2048;           // NN+1 ints
constexpr size_t OFF_DINV  = OFF_RP    + 400384;         // NN floats
constexpr size_t OFF_COL   = OFF_DINV  + 400384;         // E ints
constexpr size_t OFF_WT    = OFF_COL   + 6400000;        // 128x128 bf16 (W^T per layer)
constexpr size_t OFF_H8    = OFF_WT    + 32768;          // N*128 fp8 (mid-layer messages, prescaled)
constexpr size_t OFF_H     = OFF_H8    + 12800000;       // layer-4 split out: N*64 fp8 conv + N*64 bf16 skip; ebuf alias
constexpr size_t OFF_X     = OFF_H     + 25600000;       // N*128 bf16 (residual spine)
// ebuf (E uint = 6.4 MB) aliases OFF_H (dead before layer-4 GEMM)

// ---------------- preprocessing: radix-partition CSR build ----------------

__global__ __launch_bounds__(256) void bhist_kernel(const int* __restrict__ edst,
                                                    int* __restrict__ bcnt) {
    __shared__ int h[NB2];
    for (int i = threadIdx.x; i < NB2; i += 256) h[i] = 0;
    __syncthreads();
    const int base = blockIdx.x * TILE;
    #pragma unroll
    for (int j = 0; j < 16; ++j) {
        int e = base + j * 256 + threadIdx.x;
        if (e < NE) atomicAdd(&h[edst[e] >> 8], 1);
    }
    __syncthreads();
    for (int i = threadIdx.x; i < NB2; i += 256)
        if (h[i]) atomicAdd(&bcnt[i], h[i]);
}

__global__ __launch_bounds__(512) void bscan_kernel(const int* __restrict__ bcnt,
                                                    int* __restrict__ bbase,
                                                    int* __restrict__ bcur) {
    __shared__ int s[512];
    const int t = threadIdx.x;
    int v = (t < NB2) ? bcnt[t] : 0;
    s[t] = v;
    __syncthreads();
    for (int off = 1; off < 512; off <<= 1) {
        int a = (t >= off) ? s[t - off] : 0;
        __syncthreads();
        s[t] += a;
        __syncthreads();
    }
    int excl = s[t] - v;
    if (t < NB2) { bbase[t] = excl; bcur[t] = excl; }
    if (t == NB2 - 1) bbase[NB2] = excl + v;   // == NE
}

// edges -> bucket-ordered packed ebuf: src | (dst&255)<<24  (src < 2^17)
__global__ __launch_bounds__(256) void scatter2_kernel(const int* __restrict__ esrc,
                                                       const int* __restrict__ edst,
                                                       int* __restrict__ bcur,
                                                       unsigned int* __restrict__ ebuf) {
    __shared__ int h[NB2];
    __shared__ int cur[NB2];
    for (int i = threadIdx.x; i < NB2; i += 256) h[i] = 0;
    __syncthreads();
    const int base = blockIdx.x * TILE;
    #pragma unroll
    for (int j = 0; j < 16; ++j) {
        int e = base + j * 256 + threadIdx.x;
        if (e < NE) atomicAdd(&h[edst[e] >> 8], 1);
    }
    __syncthreads();
    for (int i = threadIdx.x; i < NB2; i += 256) {
        int c = h[i];
        cur[i] = c ? atomicAdd(&bcur[i], c) : 0;
    }
    __syncthreads();
    #pragma unroll
    for (int j = 0; j < 16; ++j) {
        int e = base + j * 256 + threadIdx.x;
        if (e < NE) {
            int s = esrc[e], d = edst[e];
            int pos = atomicAdd(&cur[d >> 8], 1);
            ebuf[pos] = (unsigned int)s | ((unsigned int)(d & 255) << 24);
        }
    }
}

__global__ __launch_bounds__(256) void csrfill2_kernel(const unsigned int* __restrict__ ebuf,
                                                       const int* __restrict__ bbase,
                                                       int* __restrict__ rp,
                                                       float* __restrict__ dinv,
                                                       int* __restrict__ col) {
    __shared__ int cnt[256];
    __shared__ int cursor[256];
    __shared__ int s[256];
    __shared__ int sbeg, send;
    const int b = blockIdx.x;
    const int t = threadIdx.x;
    if (t == 0) { sbeg = bbase[b]; send = bbase[b + 1]; }
    cnt[t] = 0;
    __syncthreads();
    const int beg = sbeg, end = send;
    const int node0 = b * BKN;

    for (int e = beg + t; e < end; e += 256)
        atomicAdd(&cnt[ebuf[e] >> 24], 1);
    __syncthreads();

    int v = cnt[t];
    s[t] = v;
    __syncthreads();
    for (int off = 1; off < 256; off <<= 1) {
        int a = (t >= off) ? s[t - off] : 0;
        __syncthreads();
        s[t] += a;
        __syncthreads();
    }
    int excl = s[t] - v;
    int gnode = node0 + t;
    if (gnode < NN) {
        rp[gnode]   = beg + excl;
        dinv[gnode] = rsqrtf((float)(v + 1));   // +1 self loop
    }
    cursor[t] = beg + excl;
    if (b == NB2 - 1 && t == 0) rp[NN] = NE;
    __syncthreads();

    for (int e = beg + t; e < end; e += 256) {
        unsigned int sd = ebuf[e];
        int pos = atomicAdd(&cursor[sd >> 24], 1);
        col[pos] = (int)(sd & 0xFFFFFFu);
    }
}

// ---------------- W pre-transpose: Wt[c][k] = bf16(W[k][c]),  c<64 from W0, c>=64 from W1 ----
__global__ __launch_bounds__(256) void wpre_kernel(const float* __restrict__ W0,
                                                   const float* __restrict__ W1,
                                                   int wstride,
                                                   unsigned short* __restrict__ Wt) {
    int e = blockIdx.x * 256 + threadIdx.x;   // grid 64 -> 16384
    int k = e >> 7, c = e & 127;
    float v = (c < 64) ? W0[(size_t)k * wstride + c] : W1[(size_t)k * wstride + (c - 64)];
    Wt[c * 128 + k] = f2bf(v);
}

// ---------------- MFMA GEMM:  H[n][:] = enc( (X[n][:] @ W) * rowScale ) ----------------
// XF32: X fp32 (layer-1 input) vs bf16 spine.
// OMODE: 1 = fp8 full row (mid layers);  2 = split (cols 0..63 -> fp8 conv, 64..127 -> bf16 skip)
constexpr int XROW = 136;   // padded shorts per LDS row

template<bool XF32, int OMODE>
__global__ __launch_bounds__(256) void gemm_mfma_kernel(const void* __restrict__ Xv,
                                                        const unsigned short* __restrict__ Wt,
                                                        const float* __restrict__ dinv,
                                                        int scaleMask,
                                                        void* __restrict__ Ho) {
    __shared__ unsigned short Wl[128 * XROW];   // W^T staged: [col][k]
    __shared__ unsigned short Xl[64 * XROW];    // X tile bf16; reused for output staging

    const int t = threadIdx.x;
    const int rowBase = blockIdx.x * 64;

    // stage Wt -> LDS: 128 rows x 16 chunks (16B)
    #pragma unroll
    for (int i = 0; i < 8; ++i) {
        int f = i * 256 + t;
        int r = f >> 4, c8 = f & 15;
        uint4 w = *(const uint4*)&Wt[r * 128 + c8 * 8];
        *(uint4*)&Wl[r * XROW + c8 * 8] = w;
    }
    // stage X tile -> LDS bf16
    if (XF32) {
        const float* X = (const float*)Xv;
        #pragma unroll
        for (int i = 0; i < 8; ++i) {
            int f = i * 256 + t;                  // 64 rows x 32 float4
            int r = f >> 5, c4 = f & 31;
            int gn = rowBase + r;
            float4 v = make_float4(0.f, 0.f, 0.f, 0.f);
            if (gn < NN) v = *(const float4*)&X[(size_t)gn * 128 + c4 * 4];
            ushort4 o;
            o.x = f2bf(v.x); o.y = f2bf(v.y); o.z = f2bf(v.z); o.w = f2bf(v.w);
            *(ushort4*)&Xl[r * XROW + c4 * 4] = o;
        }
    } else {
        const unsigned short* X = (const unsigned short*)Xv;
        #pragma unroll
        for (int i = 0; i < 4; ++i) {
            int f = i * 256 + t;                  // 64 rows x 16 uint4 chunks
            int r = f >> 4, c8 = f & 15;
            int gn = rowBase + r;
            uint4 v = make_uint4(0u, 0u, 0u, 0u);
            if (gn < NN) v = *(const uint4*)&X[(size_t)gn * 128 + c8 * 8];
            *(uint4*)&Xl[r * XROW + c8 * 8] = v;
        }
    }
    __syncthreads();

    const int w  = t >> 6;        // wave id: rows w*16 .. w*16+15
    const int l  = t & 63;
    const int lr = l & 15;        // A row / B col within 16
    const int lk = (l >> 4) * 8;  // k sub-offset within each 32-k step

    v4f acc[8];
    #pragma unroll
    for (int n = 0; n < 8; ++n) acc[n] = (v4f){0.f, 0.f, 0.f, 0.f};

    const unsigned short* ax = &Xl[(w * 16 + lr) * XROW + lk];
    const unsigned short* bx = &Wl[lr * XROW + lk];

    #pragma unroll
    for (int kk = 0; kk < 4; ++kk) {
        v8bf a = *(const v8bf*)&ax[kk * 32];
        #pragma unroll
        for (int n = 0; n < 8; ++n) {
            v8bf b = *(const v8bf*)&bx[(n * 16) * XROW + kk * 32];
            acc[n] = __builtin_amdgcn_mfma_f32_16x16x32_bf16(a, b, acc[n], 0, 0, 0);
        }
    }

    // epilogue: scale rows, pack bf16 into LDS (D: col=l&15, row=(l>>4)*4+reg)
    #pragma unroll
    for (int r_ = 0; r_ < 4; ++r_) {
        int row  = w * 16 + (l >> 4) * 4 + r_;
        int grow = rowBase + row;
        float dsc = dinv[grow < NN ? grow : NN - 1];
        #pragma unroll
        for (int n = 0; n < 8; ++n) {
            float sc = ((scaleMask >> (n >> 2)) & 1) ? dsc : 1.f;
            Xl[row * XROW + n * 16 + lr] = f2bf(acc[n][r_] * sc);
        }
    }
    __syncthreads();

    // coalesced store: 64 rows x 16 chunks
    if (OMODE == 1) {
        unsigned char* H8 = (unsigned char*)Ho;
        #pragma unroll
        for (int i = 0; i < 4; ++i) {
            int f = i * 256 + t;
            int r = f >> 4, c8 = f & 15;
            int gn = rowBase + r;
            if (gn < NN) {
                uint4 v = *(const uint4*)&Xl[r * XROW + c8 * 8];
                unsigned int lo = __builtin_amdgcn_cvt_pk_fp8_f32(bflo(v.x), bfhi(v.x), 0u, false);
                lo = __builtin_amdgcn_cvt_pk_fp8_f32(bflo(v.y), bfhi(v.y), lo, true);
                unsigned int hi = __builtin_amdgcn_cvt_pk_fp8_f32(bflo(v.z), bfhi(v.z), 0u, false);
                hi = __builtin_amdgcn_cvt_pk_fp8_f32(bflo(v.w), bfhi(v.w), hi, true);
                *(uint2*)&H8[(size_t)gn * 128 + c8 * 8] = make_uint2(lo, hi);
            }
        }
    } else {
        // split: conv half fp8 (prescaled via scaleMask bit0), skip half bf16
        unsigned char*  h8o   = (unsigned char*)Ho;
        unsigned short* skipb = (unsigned short*)((char*)Ho + (size_t)NN * 64);
        #pragma unroll
        for (int i = 0; i < 4; ++i) {
            int f = i * 256 + t;
            int r = f >> 4, c8 = f & 15;
            int gn = rowBase + r;
            if (gn < NN) {
                uint4 v = *(const uint4*)&Xl[r * XROW + c8 * 8];
                if (c8 < 8) {
                    unsigned int lo = __builtin_amdgcn_cvt_pk_fp8_f32(bflo(v.x), bfhi(v.x), 0u, false);
                    lo = __builtin_amdgcn_cvt_pk_fp8_f32(bflo(v.y), bfhi(v.y), lo, true);
                    unsigned int hi = __builtin_amdgcn_cvt_pk_fp8_f32(bflo(v.z), bfhi(v.z), 0u, false);
                    hi = __builtin_amdgcn_cvt_pk_fp8_f32(bflo(v.w), bfhi(v.w), hi, true);
                    *(uint2*)&h8o[(size_t)gn * 64 + c8 * 8] = make_uint2(lo, hi);
                } else {
                    *(uint4*)&skipb[(size_t)gn * 64 + (c8 - 8) * 8] = v;
                }
            }
        }
    }
}

// ---------------- aggregation: 128-feature layers (R9 structure, 16-deep unroll) ----------------
// H8: fp8 rows (prescaled). out = relu(dinv[i]*(H[i] + sum_e H[col[e]]) + bias + Xold)
template<bool XF32>
__global__ __launch_bounds__(256) void agg128_kernel(const unsigned char* __restrict__ H8,
                                                     const void* __restrict__ Xoldv,
                                                     const int* __restrict__ rp,
                                                     const int* __restrict__ col,
                                                     const float* __restrict__ dinv,
                                                     const float* __restrict__ bias,
                                                     unsigned int* __restrict__ Xnew) {
    const int wid  = threadIdx.x >> 6;
    const int lane = threadIdx.x & 63;
    const int i = blockIdx.x * 4 + wid;
    if (i >= NN) return;

    const unsigned short* __restrict__ Hs = (const unsigned short*)H8;   // 2 fp8 per ushort

    const float di = dinv[i];
    const float2 b2 = ((const float2*)bias)[lane];
    float xox, xoy;
    if (XF32) {
        float2 xo = ((const float2*)Xoldv)[(size_t)i * 64 + lane];
        xox = xo.x; xoy = xo.y;
    } else {
        unsigned int xo = ((const unsigned int*)Xoldv)[(size_t)i * 64 + lane];
        xox = bflo(xo); xoy = bfhi(xo);
    }

    v2f sf = fp8x2_to_f32(Hs[(size_t)i * 64 + lane]);   // self term
    float ax = sf.x, ay = sf.y;

    const int beg = rp[i], end = rp[i + 1];
    int e = beg;
    for (; e + 16 <= end; e += 16) {
        unsigned int u[16];
        #pragma unroll
        for (int j = 0; j < 16; ++j) u[j] = Hs[(size_t)col[e + j] * 64 + lane];
        v2f m[16];
        #pragma unroll
        for (int j = 0; j < 16; ++j) m[j] = fp8x2_to_f32(u[j]);
        v2f s01 = ((m[0] + m[1]) + (m[2] + m[3])) + ((m[4] + m[5]) + (m[6] + m[7]));
        v2f s02 = ((m[8] + m[9]) + (m[10] + m[11])) + ((m[12] + m[13]) + (m[14] + m[15]));
        ax += s01.x + s02.x;
        ay += s01.y + s02.y;
    }
    for (; e + 4 <= end; e += 4) {
        unsigned int u0 = Hs[(size_t)col[e]     * 64 + lane];
        unsigned int u1 = Hs[(size_t)col[e + 1] * 64 + lane];
        unsigned int u2 = Hs[(size_t)col[e + 2] * 64 + lane];
        unsigned int u3 = Hs[(size_t)col[e + 3] * 64 + lane];
        v2f m0 = fp8x2_to_f32(u0), m1 = fp8x2_to_f32(u1);
        v2f m2 = fp8x2_to_f32(u2), m3 = fp8x2_to_f32(u3);
        ax += (m0.x + m1.x) + (m2.x + m3.x);
        ay += (m0.y + m1.y) + (m2.y + m3.y);
    }
    for (; e < end; ++e) {
        v2f m = fp8x2_to_f32(Hs[(size_t)col[e] * 64 + lane]);
        ax += m.x;
        ay += m.y;
    }

    float ox = fmaxf(di * ax + b2.x + xox, 0.f);
    float oy = fmaxf(di * ay + b2.y + xoy, 0.f);
    Xnew[(size_t)i * 64 + lane] = pack2bf(ox, oy);
}

// ---------------- final layer: fp8 conv gathers (64B rows) + bf16 skip stream ----------------
__global__ __launch_bounds__(256) void aggout_kernel(const unsigned char* __restrict__ h8o,
                                                     const unsigned short* __restrict__ skipb,
                                                     const int* __restrict__ rp,
                                                     const int* __restrict__ col,
                                                     const float* __restrict__ dinv,
                                                     const float* __restrict__ bias,
                                                     float* __restrict__ out) {
    const int wid  = threadIdx.x >> 6;
    const int lane = threadIdx.x & 63;
    const int i = blockIdx.x * 4 + wid;
    if (i >= NN) return;

    const float di = dinv[i];
    const float b  = bias[lane];
    const float sk = bf2f(skipb[(size_t)i * 64 + lane]);

    float a = fp8b(h8o[(size_t)i * 64 + lane]);   // self term
    const int beg = rp[i], end = rp[i + 1];
    int e = beg;
    for (; e + 8 <= end; e += 8) {
        unsigned char c0 = h8o[(size_t)col[e]     * 64 + lane];
        unsigned char c1 = h8o[(size_t)col[e + 1] * 64 + lane];
        unsigned char c2 = h8o[(size_t)col[e + 2] * 64 + lane];
        unsigned char c3 = h8o[(size_t)col[e + 3] * 64 + lane];
        unsigned char c4 = h8o[(size_t)col[e + 4] * 64 + lane];
        unsigned char c5 = h8o[(size_t)col[e + 5] * 64 + lane];
        unsigned char c6 = h8o[(size_t)col[e + 6] * 64 + lane];
        unsigned char c7 = h8o[(size_t)col[e + 7] * 64 + lane];
        a += ((fp8b(c0) + fp8b(c1)) + (fp8b(c2) + fp8b(c3))) +
             ((fp8b(c4) + fp8b(c5)) + (fp8b(c6) + fp8b(c7)));
    }
    for (; e + 4 <= end; e += 4) {
        unsigned char c0 = h8o[(size_t)col[e]     * 64 + lane];
        unsigned char c1 = h8o[(size_t)col[e + 1] * 64 + lane];
        unsigned char c2 = h8o[(size_t)col[e + 2] * 64 + lane];
        unsigned char c3 = h8o[(size_t)col[e + 3] * 64 + lane];
        a += (fp8b(c0) + fp8b(c1)) + (fp8b(c2) + fp8b(c3));
    }
    for (; e < end; ++e) a += fp8b(h8o[(size_t)col[e] * 64 + lane]);

    out[(size_t)i * 64 + lane] = di * a + b + sk;
}

// ---------------- launch ----------------
extern "C" void kernel_launch(void* const* d_in, const int* in_sizes, int n_in,
                              void* d_out, int out_size, void* d_ws, size_t ws_size,
                              hipStream_t stream) {
    const float* x      = (const float*)d_in[0];
    const int*   ei     = (const int*)d_in[1];
    const float* W_in   = (const float*)d_in[2];
    const float* b_in   = (const float*)d_in[3];
    const float* W_mid0 = (const float*)d_in[4];
    const float* b_mid0 = (const float*)d_in[5];
    const float* W_mid1 = (const float*)d_in[6];
    const float* b_mid1 = (const float*)d_in[7];
    const float* W_out  = (const float*)d_in[8];
    const float* b_out  = (const float*)d_in[9];
    const float* W_skip = (const float*)d_in[10];

    const int* esrc = ei;        // edge_index[0]
    const int* edst = ei + NE;   // edge_index[1]

    char* ws = (char*)d_ws;
    int*   bcnt   = (int*)  (ws + OFF_BCNT);
    int*   bbase  = (int*)  (ws + OFF_BBASE);
    int*   bcur   = (int*)  (ws + OFF_BCUR);
    int*   rp     = (int*)  (ws + OFF_RP);
    float* dinv   = (float*)(ws + OFF_DINV);
    int*   col    = (int*)  (ws + OFF_COL);
    unsigned short* wt   = (unsigned short*)(ws + OFF_WT);
    unsigned char*  h8   = (unsigned char*) (ws + OFF_H8);
    unsigned char*  h8o  = (unsigned char*) (ws + OFF_H);              // layer-4 conv (fp8)
    unsigned short* skipb = (unsigned short*)(ws + OFF_H + (size_t)NN * 64);  // layer-4 skip (bf16)
    unsigned int*   ebuf = (unsigned int*)  (ws + OFF_H);   // alias: dead before layer-4 GEMM
    unsigned short* xbuf = (unsigned short*)(ws + OFF_X);
    unsigned int*   xbufw = (unsigned int*) (ws + OFF_X);
    float* outp   = (float*)d_out;

    const int gemmGrid = (NN + 63) / 64;             // 1563
    const int aggGrid  = (NN + 3) / 4;               // 25000

    // ---- graph preprocessing ----
    (void)hipMemsetAsync(bcnt, 0, (size_t)(NB2 + 1) * 4, stream);
    bhist_kernel<<<NT, 256, 0, stream>>>(edst, bcnt);
    bscan_kernel<<<1, 512, 0, stream>>>(bcnt, bbase, bcur);
    scatter2_kernel<<<NT, 256, 0, stream>>>(esrc, edst, bcur, ebuf);
    csrfill2_kernel<<<NB2, 256, 0, stream>>>(ebuf, bbase, rp, dinv, col);

    // ---- layer 1 (reads fp32 x; fp8 messages; bf16 spine out) ----
    wpre_kernel<<<64, 256, 0, stream>>>(W_in, W_in + 64, 128, wt);
    gemm_mfma_kernel<true, 1><<<gemmGrid, 256, 0, stream>>>(x, wt, dinv, 3, h8);
    agg128_kernel<true><<<aggGrid, 256, 0, stream>>>(h8, x, rp, col, dinv, b_in, xbufw);

    // ---- layer 2 ----
    wpre_kernel<<<64, 256, 0, stream>>>(W_mid0, W_mid0 + 64, 128, wt);
    gemm_mfma_kernel<false, 1><<<gemmGrid, 256, 0, stream>>>(xbuf, wt, dinv, 3, h8);
    agg128_kernel<false><<<aggGrid, 256, 0, stream>>>(h8, xbuf, rp, col, dinv, b_mid0, xbufw);

    // ---- layer 3 ----
    wpre_kernel<<<64, 256, 0, stream>>>(W_mid1, W_mid1 + 64, 128, wt);
    gemm_mfma_kernel<false, 1><<<gemmGrid, 256, 0, stream>>>(xbuf, wt, dinv, 3, h8);
    agg128_kernel<false><<<aggGrid, 256, 0, stream>>>(h8, xbuf, rp, col, dinv, b_mid1, xbufw);

    // ---- layer 4: fused [W_out | W_skip_out] GEMM, split fp8-conv / bf16-skip outputs ----
    wpre_kernel<<<64, 256, 0, stream>>>(W_out, W_skip, 64, wt);
    gemm_mfma_kernel<false, 2><<<gemmGrid, 256, 0, stream>>>(xbuf, wt, dinv, 1, (void*)h8o);
    aggout_kernel<<<aggGrid, 256, 0, stream>>>(h8o, skipb, rp, col, dinv, b_out, outp);
}

// Round 13
// 335.830 us; speedup vs baseline: 1.0811x; 1.0129x over previous
//
#include <hip/hip_runtime.h>
#include <hip/hip_bf16.h>

// ---------------- problem constants ----------------
constexpr int NN = 100000;   // nodes
constexpr int NE = 1600000;  // directed edges
constexpr int BKN  = 256;                  // nodes per bucket
constexpr int NB2  = (NN + BKN - 1) / BKN; // 391 buckets
constexpr int TILE = 4096;                 // edges per scatter block
constexpr int NT   = (NE + TILE - 1) / TILE; // 391 tiles

// ---------------- bf16 / fp8 helpers ----------------
__device__ __forceinline__ unsigned short f2bf(float f) {
    unsigned int u = __float_as_uint(f);
    unsigned int r = (u + 0x7fffu + ((u >> 16) & 1u)) >> 16;
    return (unsigned short)r;
}
__device__ __forceinline__ float bflo(unsigned int u) { return __uint_as_float(u << 16); }
__device__ __forceinline__ float bfhi(unsigned int u) { return __uint_as_float(u & 0xffff0000u); }
__device__ __forceinline__ float bf2f(unsigned short h) { return __uint_as_float(((unsigned int)h) << 16); }
__device__ __forceinline__ unsigned int pack2bf(float lo, float hi) {
    return (unsigned int)f2bf(lo) | ((unsigned int)f2bf(hi) << 16);
}

typedef __bf16 v8bf __attribute__((ext_vector_type(8)));
typedef float  v4f  __attribute__((ext_vector_type(4)));
typedef float  v2f  __attribute__((ext_vector_type(2)));

__device__ __forceinline__ v2f fp8x2_to_f32(unsigned int u) {
    v2f t = __builtin_amdgcn_cvt_pk_f32_fp8(u, false);   // bytes 0,1 -> {x,y}
    return t;
}
__device__ __forceinline__ float fp8b(unsigned char b) {
    v2f t = __builtin_amdgcn_cvt_pk_f32_fp8((unsigned int)b, false);
    return t.x;
}

// ---------------- workspace layout (bytes) ----------------
constexpr size_t OFF_BCNT  = 0;                          // NB2+1 ints
constexpr size_t OFF_BBASE = OFF_BCNT  + 2048;           // NB2+1 ints
constexpr size_t OFF_BCUR  = OFF_BBASE + 2048;           // NB2 ints
constexpr size_t OFF_RP    = OFF_BCUR  + 2048;           // NN+1 ints
constexpr size_t OFF_DINV  = OFF_RP    + 400384;         // NN floats
constexpr size_t OFF_COL   = OFF_DINV  + 400384;         // E ints
constexpr size_t OFF_WT    = OFF_COL   + 6400000;        // 128x128 bf16 (W^T per layer)
constexpr size_t OFF_H8    = OFF_WT    + 32768;          // N*128 fp8 (mid-layer messages, prescaled)
constexpr size_t OFF_H     = OFF_H8    + 12800000;       // layer-4 split out: N*64 fp8 conv + N*64 bf16 skip; ebuf alias
constexpr size_t OFF_X     = OFF_H     + 25600000;       // N*128 bf16 (residual spine)
// ebuf (E uint = 6.4 MB) aliases OFF_H (dead before layer-4 GEMM)

// ---------------- preprocessing: radix-partition CSR build ----------------

__global__ __launch_bounds__(256) void bhist_kernel(const int* __restrict__ edst,
                                                    int* __restrict__ bcnt) {
    __shared__ int h[NB2];
    for (int i = threadIdx.x; i < NB2; i += 256) h[i] = 0;
    __syncthreads();
    const int base = blockIdx.x * TILE;
    #pragma unroll
    for (int j = 0; j < 16; ++j) {
        int e = base + j * 256 + threadIdx.x;
        if (e < NE) atomicAdd(&h[edst[e] >> 8], 1);
    }
    __syncthreads();
    for (int i = threadIdx.x; i < NB2; i += 256)
        if (h[i]) atomicAdd(&bcnt[i], h[i]);
}

__global__ __launch_bounds__(512) void bscan_kernel(const int* __restrict__ bcnt,
                                                    int* __restrict__ bbase,
                                                    int* __restrict__ bcur) {
    __shared__ int s[512];
    const int t = threadIdx.x;
    int v = (t < NB2) ? bcnt[t] : 0;
    s[t] = v;
    __syncthreads();
    for (int off = 1; off < 512; off <<= 1) {
        int a = (t >= off) ? s[t - off] : 0;
        __syncthreads();
        s[t] += a;
        __syncthreads();
    }
    int excl = s[t] - v;
    if (t < NB2) { bbase[t] = excl; bcur[t] = excl; }
    if (t == NB2 - 1) bbase[NB2] = excl + v;   // == NE
}

// edges -> bucket-ordered packed ebuf via LDS counting sort; write-out is slot-ordered so
// consecutive lanes write consecutive addresses of each bucket run (full-line write combining).
__global__ __launch_bounds__(256) void scatter2_kernel(const int* __restrict__ esrc,
                                                       const int* __restrict__ edst,
                                                       int* __restrict__ bcur,
                                                       unsigned int* __restrict__ ebuf) {
    __shared__ int h[NB2];                 // hist, then local rank cursor
    __shared__ int loff[NB2];              // local exclusive offsets
    __shared__ int gbase[NB2];             // global base per bucket
    __shared__ int sc[512];                // scan workspace
    __shared__ unsigned int   stage[TILE]; // 16KB: packed edges in bucket order
    __shared__ unsigned short sbkt[TILE];  // 8KB: bucket id per slot
    const int t = threadIdx.x;
    const int base = blockIdx.x * TILE;

    for (int i = t; i < NB2; i += 256) h[i] = 0;
    __syncthreads();

    int es[16], ed[16];
    #pragma unroll
    for (int j = 0; j < 16; ++j) {
        int e = base + j * 256 + t;
        if (e < NE) {
            es[j] = esrc[e];
            ed[j] = edst[e];
            atomicAdd(&h[ed[j] >> 8], 1);
        } else {
            es[j] = -1; ed[j] = 0;
        }
    }
    __syncthreads();

    // local exclusive scan of h (512-wide Hillis-Steele, 2 slots/thread)
    sc[t]       = (t < NB2)       ? h[t]       : 0;
    sc[t + 256] = (t + 256 < NB2) ? h[t + 256] : 0;
    __syncthreads();
    for (int off = 1; off < 512; off <<= 1) {
        int a0 = (t >= off)       ? sc[t - off]       : 0;
        int a1 = (t + 256 >= off) ? sc[t + 256 - off] : 0;
        __syncthreads();
        sc[t] += a0; sc[t + 256] += a1;
        __syncthreads();
    }
    if (t < NB2) {
        loff[t]  = sc[t] - h[t];
        gbase[t] = h[t] ? atomicAdd(&bcur[t], h[t]) : 0;
    }
    if (t + 256 < NB2) {
        loff[t + 256]  = sc[t + 256] - h[t + 256];
        gbase[t + 256] = h[t + 256] ? atomicAdd(&bcur[t + 256], h[t + 256]) : 0;
    }
    __syncthreads();
    for (int i = t; i < NB2; i += 256) h[i] = 0;   // reuse as rank cursor
    __syncthreads();

    // rank + stage into bucket-sorted LDS order
    #pragma unroll
    for (int j = 0; j < 16; ++j) {
        if (es[j] >= 0) {
            int b = ed[j] >> 8;
            int r = atomicAdd(&h[b], 1);
            int slot = loff[b] + r;
            stage[slot] = (unsigned int)es[j] | ((unsigned int)(ed[j] & 255) << 24);
            sbkt[slot]  = (unsigned short)b;
        }
    }
    __syncthreads();

    // slot-ordered coalesced write-out
    int nval = NE - base; if (nval > TILE) nval = TILE;
    for (int j = t; j < nval; j += 256) {
        int b = sbkt[j];
        ebuf[gbase[b] + (j - loff[b])] = stage[j];
    }
}

__global__ __launch_bounds__(256) void csrfill2_kernel(const unsigned int* __restrict__ ebuf,
                                                       const int* __restrict__ bbase,
                                                       int* __restrict__ rp,
                                                       float* __restrict__ dinv,
                                                       int* __restrict__ col) {
    __shared__ int cnt[256];
    __shared__ int cursor[256];
    __shared__ int s[256];
    __shared__ int sbeg, send;
    const int b = blockIdx.x;
    const int t = threadIdx.x;
    if (t == 0) { sbeg = bbase[b]; send = bbase[b + 1]; }
    cnt[t] = 0;
    __syncthreads();
    const int beg = sbeg, end = send;
    const int node0 = b * BKN;

    for (int e = beg + t; e < end; e += 256)
        atomicAdd(&cnt[ebuf[e] >> 24], 1);
    __syncthreads();

    int v = cnt[t];
    s[t] = v;
    __syncthreads();
    for (int off = 1; off < 256; off <<= 1) {
        int a = (t >= off) ? s[t - off] : 0;
        __syncthreads();
        s[t] += a;
        __syncthreads();
    }
    int excl = s[t] - v;
    int gnode = node0 + t;
    if (gnode < NN) {
        rp[gnode]   = beg + excl;
        dinv[gnode] = rsqrtf((float)(v + 1));   // +1 self loop
    }
    cursor[t] = beg + excl;
    if (b == NB2 - 1 && t == 0) rp[NN] = NE;
    __syncthreads();

    for (int e = beg + t; e < end; e += 256) {
        unsigned int sd = ebuf[e];
        int pos = atomicAdd(&cursor[sd >> 24], 1);
        col[pos] = (int)(sd & 0xFFFFFFu);
    }
}

// ---------------- W pre-transpose: Wt[c][k] = bf16(W[k][c]),  c<64 from W0, c>=64 from W1 ----
__global__ __launch_bounds__(256) void wpre_kernel(const float* __restrict__ W0,
                                                   const float* __restrict__ W1,
                                                   int wstride,
                                                   unsigned short* __restrict__ Wt) {
    int e = blockIdx.x * 256 + threadIdx.x;   // grid 64 -> 16384
    int k = e >> 7, c = e & 127;
    float v = (c < 64) ? W0[(size_t)k * wstride + c] : W1[(size_t)k * wstride + (c - 64)];
    Wt[c * 128 + k] = f2bf(v);
}

// ---------------- MFMA GEMM:  H[n][:] = enc( (X[n][:] @ W) * rowScale ) ----------------
// XF32: X fp32 (layer-1 input) vs bf16 spine.
// OMODE: 1 = fp8 full row (mid layers);  2 = split (cols 0..63 -> fp8 conv, 64..127 -> bf16 skip)
constexpr int XROW = 136;   // padded shorts per LDS row

template<bool XF32, int OMODE>
__global__ __launch_bounds__(256) void gemm_mfma_kernel(const void* __restrict__ Xv,
                                                        const unsigned short* __restrict__ Wt,
                                                        const float* __restrict__ dinv,
                                                        int scaleMask,
                                                        void* __restrict__ Ho) {
    __shared__ unsigned short Wl[128 * XROW];   // W^T staged: [col][k]
    __shared__ unsigned short Xl[64 * XROW];    // X tile bf16; reused for output staging

    const int t = threadIdx.x;
    const int rowBase = blockIdx.x * 64;

    // stage Wt -> LDS: 128 rows x 16 chunks (16B)
    #pragma unroll
    for (int i = 0; i < 8; ++i) {
        int f = i * 256 + t;
        int r = f >> 4, c8 = f & 15;
        uint4 w = *(const uint4*)&Wt[r * 128 + c8 * 8];
        *(uint4*)&Wl[r * XROW + c8 * 8] = w;
    }
    // stage X tile -> LDS bf16
    if (XF32) {
        const float* X = (const float*)Xv;
        #pragma unroll
        for (int i = 0; i < 8; ++i) {
            int f = i * 256 + t;                  // 64 rows x 32 float4
            int r = f >> 5, c4 = f & 31;
            int gn = rowBase + r;
            float4 v = make_float4(0.f, 0.f, 0.f, 0.f);
            if (gn < NN) v = *(const float4*)&X[(size_t)gn * 128 + c4 * 4];
            ushort4 o;
            o.x = f2bf(v.x); o.y = f2bf(v.y); o.z = f2bf(v.z); o.w = f2bf(v.w);
            *(ushort4*)&Xl[r * XROW + c4 * 4] = o;
        }
    } else {
        const unsigned short* X = (const unsigned short*)Xv;
        #pragma unroll
        for (int i = 0; i < 4; ++i) {
            int f = i * 256 + t;                  // 64 rows x 16 uint4 chunks
            int r = f >> 4, c8 = f & 15;
            int gn = rowBase + r;
            uint4 v = make_uint4(0u, 0u, 0u, 0u);
            if (gn < NN) v = *(const uint4*)&X[(size_t)gn * 128 + c8 * 8];
            *(uint4*)&Xl[r * XROW + c8 * 8] = v;
        }
    }
    __syncthreads();

    const int w  = t >> 6;        // wave id: rows w*16 .. w*16+15
    const int l  = t & 63;
    const int lr = l & 15;        // A row / B col within 16
    const int lk = (l >> 4) * 8;  // k sub-offset within each 32-k step

    v4f acc[8];
    #pragma unroll
    for (int n = 0; n < 8; ++n) acc[n] = (v4f){0.f, 0.f, 0.f, 0.f};

    const unsigned short* ax = &Xl[(w * 16 + lr) * XROW + lk];
    const unsigned short* bx = &Wl[lr * XROW + lk];

    #pragma unroll
    for (int kk = 0; kk < 4; ++kk) {
        v8bf a = *(const v8bf*)&ax[kk * 32];
        #pragma unroll
        for (int n = 0; n < 8; ++n) {
            v8bf b = *(const v8bf*)&bx[(n * 16) * XROW + kk * 32];
            acc[n] = __builtin_amdgcn_mfma_f32_16x16x32_bf16(a, b, acc[n], 0, 0, 0);
        }
    }

    // epilogue: scale rows, pack bf16 into LDS (D: col=l&15, row=(l>>4)*4+reg)
    #pragma unroll
    for (int r_ = 0; r_ < 4; ++r_) {
        int row  = w * 16 + (l >> 4) * 4 + r_;
        int grow = rowBase + row;
        float dsc = dinv[grow < NN ? grow : NN - 1];
        #pragma unroll
        for (int n = 0; n < 8; ++n) {
            float sc = ((scaleMask >> (n >> 2)) & 1) ? dsc : 1.f;
            Xl[row * XROW + n * 16 + lr] = f2bf(acc[n][r_] * sc);
        }
    }
    __syncthreads();

    // coalesced store: 64 rows x 16 chunks
    if (OMODE == 1) {
        unsigned char* H8 = (unsigned char*)Ho;
        #pragma unroll
        for (int i = 0; i < 4; ++i) {
            int f = i * 256 + t;
            int r = f >> 4, c8 = f & 15;
            int gn = rowBase + r;
            if (gn < NN) {
                uint4 v = *(const uint4*)&Xl[r * XROW + c8 * 8];
                unsigned int lo = __builtin_amdgcn_cvt_pk_fp8_f32(bflo(v.x), bfhi(v.x), 0u, false);
                lo = __builtin_amdgcn_cvt_pk_fp8_f32(bflo(v.y), bfhi(v.y), lo, true);
                unsigned int hi = __builtin_amdgcn_cvt_pk_fp8_f32(bflo(v.z), bfhi(v.z), 0u, false);
                hi = __builtin_amdgcn_cvt_pk_fp8_f32(bflo(v.w), bfhi(v.w), hi, true);
                *(uint2*)&H8[(size_t)gn * 128 + c8 * 8] = make_uint2(lo, hi);
            }
        }
    } else {
        // split: conv half fp8 (prescaled via scaleMask bit0), skip half bf16
        unsigned char*  h8o   = (unsigned char*)Ho;
        unsigned short* skipb = (unsigned short*)((char*)Ho + (size_t)NN * 64);
        #pragma unroll
        for (int i = 0; i < 4; ++i) {
            int f = i * 256 + t;
            int r = f >> 4, c8 = f & 15;
            int gn = rowBase + r;
            if (gn < NN) {
                uint4 v = *(const uint4*)&Xl[r * XROW + c8 * 8];
                if (c8 < 8) {
                    unsigned int lo = __builtin_amdgcn_cvt_pk_fp8_f32(bflo(v.x), bfhi(v.x), 0u, false);
                    lo = __builtin_amdgcn_cvt_pk_fp8_f32(bflo(v.y), bfhi(v.y), lo, true);
                    unsigned int hi = __builtin_amdgcn_cvt_pk_fp8_f32(bflo(v.z), bfhi(v.z), 0u, false);
                    hi = __builtin_amdgcn_cvt_pk_fp8_f32(bflo(v.w), bfhi(v.w), hi, true);
                    *(uint2*)&h8o[(size_t)gn * 64 + c8 * 8] = make_uint2(lo, hi);
                } else {
                    *(uint4*)&skipb[(size_t)gn * 64 + (c8 - 8) * 8] = v;
                }
            }
        }
    }
}

// ---------------- aggregation: 128-feature layers (R9 structure, 8-deep unroll) ----------------
// H8: fp8 rows (prescaled). out = relu(dinv[i]*(H[i] + sum_e H[col[e]]) + bias + Xold)
template<bool XF32>
__global__ __launch_bounds__(256) void agg128_kernel(const unsigned char* __restrict__ H8,
                                                     const void* __restrict__ Xoldv,
                                                     const int* __restrict__ rp,
                                                     const int* __restrict__ col,
                                                     const float* __restrict__ dinv,
                                                     const float* __restrict__ bias,
                                                     unsigned int* __restrict__ Xnew) {
    const int wid  = threadIdx.x >> 6;
    const int lane = threadIdx.x & 63;
    const int i = blockIdx.x * 4 + wid;
    if (i >= NN) return;

    const unsigned short* __restrict__ Hs = (const unsigned short*)H8;   // 2 fp8 per ushort

    const float di = dinv[i];
    const float2 b2 = ((const float2*)bias)[lane];
    float xox, xoy;
    if (XF32) {
        float2 xo = ((const float2*)Xoldv)[(size_t)i * 64 + lane];
        xox = xo.x; xoy = xo.y;
    } else {
        unsigned int xo = ((const unsigned int*)Xoldv)[(size_t)i * 64 + lane];
        xox = bflo(xo); xoy = bfhi(xo);
    }

    v2f sf = fp8x2_to_f32(Hs[(size_t)i * 64 + lane]);   // self term
    float ax = sf.x, ay = sf.y;

    const int beg = rp[i], end = rp[i + 1];
    int e = beg;
    for (; e + 8 <= end; e += 8) {
        int s0 = col[e],     s1 = col[e + 1], s2 = col[e + 2], s3 = col[e + 3];
        int s4 = col[e + 4], s5 = col[e + 5], s6 = col[e + 6], s7 = col[e + 7];
        unsigned int u0 = Hs[(size_t)s0 * 64 + lane];
        unsigned int u1 = Hs[(size_t)s1 * 64 + lane];
        unsigned int u2 = Hs[(size_t)s2 * 64 + lane];
        unsigned int u3 = Hs[(size_t)s3 * 64 + lane];
        unsigned int u4 = Hs[(size_t)s4 * 64 + lane];
        unsigned int u5 = Hs[(size_t)s5 * 64 + lane];
        unsigned int u6 = Hs[(size_t)s6 * 64 + lane];
        unsigned int u7 = Hs[(size_t)s7 * 64 + lane];
        v2f m0 = fp8x2_to_f32(u0), m1 = fp8x2_to_f32(u1);
        v2f m2 = fp8x2_to_f32(u2), m3 = fp8x2_to_f32(u3);
        v2f m4 = fp8x2_to_f32(u4), m5 = fp8x2_to_f32(u5);
        v2f m6 = fp8x2_to_f32(u6), m7 = fp8x2_to_f32(u7);
        ax += ((m0.x + m1.x) + (m2.x + m3.x)) + ((m4.x + m5.x) + (m6.x + m7.x));
        ay += ((m0.y + m1.y) + (m2.y + m3.y)) + ((m4.y + m5.y) + (m6.y + m7.y));
    }
    for (; e + 4 <= end; e += 4) {
        int s0 = col[e], s1 = col[e + 1], s2 = col[e + 2], s3 = col[e + 3];
        unsigned int u0 = Hs[(size_t)s0 * 64 + lane];
        unsigned int u1 = Hs[(size_t)s1 * 64 + lane];
        unsigned int u2 = Hs[(size_t)s2 * 64 + lane];
        unsigned int u3 = Hs[(size_t)s3 * 64 + lane];
        v2f m0 = fp8x2_to_f32(u0), m1 = fp8x2_to_f32(u1);
        v2f m2 = fp8x2_to_f32(u2), m3 = fp8x2_to_f32(u3);
        ax += (m0.x + m1.x) + (m2.x + m3.x);
        ay += (m0.y + m1.y) + (m2.y + m3.y);
    }
    for (; e < end; ++e) {
        v2f m = fp8x2_to_f32(Hs[(size_t)col[e] * 64 + lane]);
        ax += m.x;
        ay += m.y;
    }

    float ox = fmaxf(di * ax + b2.x + xox, 0.f);
    float oy = fmaxf(di * ay + b2.y + xoy, 0.f);
    Xnew[(size_t)i * 64 + lane] = pack2bf(ox, oy);
}

// ---------------- final layer: fp8 conv gathers (64B rows) + bf16 skip stream ----------------
__global__ __launch_bounds__(256) void aggout_kernel(const unsigned char* __restrict__ h8o,
                                                     const unsigned short* __restrict__ skipb,
                                                     const int* __restrict__ rp,
                                                     const int* __restrict__ col,
                                                     const float* __restrict__ dinv,
                                                     const float* __restrict__ bias,
                                                     float* __restrict__ out) {
    const int wid  = threadIdx.x >> 6;
    const int lane = threadIdx.x & 63;
    const int i = blockIdx.x * 4 + wid;
    if (i >= NN) return;

    const float di = dinv[i];
    const float b  = bias[lane];
    const float sk = bf2f(skipb[(size_t)i * 64 + lane]);

    float a = fp8b(h8o[(size_t)i * 64 + lane]);   // self term
    const int beg = rp[i], end = rp[i + 1];
    int e = beg;
    for (; e + 8 <= end; e += 8) {
        unsigned char c0 = h8o[(size_t)col[e]     * 64 + lane];
        unsigned char c1 = h8o[(size_t)col[e + 1] * 64 + lane];
        unsigned char c2 = h8o[(size_t)col[e + 2] * 64 + lane];
        unsigned char c3 = h8o[(size_t)col[e + 3] * 64 + lane];
        unsigned char c4 = h8o[(size_t)col[e + 4] * 64 + lane];
        unsigned char c5 = h8o[(size_t)col[e + 5] * 64 + lane];
        unsigned char c6 = h8o[(size_t)col[e + 6] * 64 + lane];
        unsigned char c7 = h8o[(size_t)col[e + 7] * 64 + lane];
        a += ((fp8b(c0) + fp8b(c1)) + (fp8b(c2) + fp8b(c3))) +
             ((fp8b(c4) + fp8b(c5)) + (fp8b(c6) + fp8b(c7)));
    }
    for (; e + 4 <= end; e += 4) {
        unsigned char c0 = h8o[(size_t)col[e]     * 64 + lane];
        unsigned char c1 = h8o[(size_t)col[e + 1] * 64 + lane];
        unsigned char c2 = h8o[(size_t)col[e + 2] * 64 + lane];
        unsigned char c3 = h8o[(size_t)col[e + 3] * 64 + lane];
        a += (fp8b(c0) + fp8b(c1)) + (fp8b(c2) + fp8b(c3));
    }
    for (; e < end; ++e) a += fp8b(h8o[(size_t)col[e] * 64 + lane]);

    out[(size_t)i * 64 + lane] = di * a + b + sk;
}

// ---------------- launch ----------------
extern "C" void kernel_launch(void* const* d_in, const int* in_sizes, int n_in,
                              void* d_out, int out_size, void* d_ws, size_t ws_size,
                              hipStream_t stream) {
    const float* x      = (const float*)d_in[0];
    const int*   ei     = (const int*)d_in[1];
    const float* W_in   = (const float*)d_in[2];
    const float* b_in   = (const float*)d_in[3];
    const float* W_mid0 = (const float*)d_in[4];
    const float* b_mid0 = (const float*)d_in[5];
    const float* W_mid1 = (const float*)d_in[6];
    const float* b_mid1 = (const float*)d_in[7];
    const float* W_out  = (const float*)d_in[8];
    const float* b_out  = (const float*)d_in[9];
    const float* W_skip = (const float*)d_in[10];

    const int* esrc = ei;        // edge_index[0]
    const int* edst = ei + NE;   // edge_index[1]

    char* ws = (char*)d_ws;
    int*   bcnt   = (int*)  (ws + OFF_BCNT);
    int*   bbase  = (int*)  (ws + OFF_BBASE);
    int*   bcur   = (int*)  (ws + OFF_BCUR);
    int*   rp     = (int*)  (ws + OFF_RP);
    float* dinv   = (float*)(ws + OFF_DINV);
    int*   col    = (int*)  (ws + OFF_COL);
    unsigned short* wt   = (unsigned short*)(ws + OFF_WT);
    unsigned char*  h8   = (unsigned char*) (ws + OFF_H8);
    unsigned char*  h8o  = (unsigned char*) (ws + OFF_H);              // layer-4 conv (fp8)
    unsigned short* skipb = (unsigned short*)(ws + OFF_H + (size_t)NN * 64);  // layer-4 skip (bf16)
    unsigned int*   ebuf = (unsigned int*)  (ws + OFF_H);   // alias: dead before layer-4 GEMM
    unsigned short* xbuf = (unsigned short*)(ws + OFF_X);
    unsigned int*   xbufw = (unsigned int*) (ws + OFF_X);
    float* outp   = (float*)d_out;

    const int gemmGrid = (NN + 63) / 64;             // 1563
    const int aggGrid  = (NN + 3) / 4;               // 25000

    // ---- graph preprocessing ----
    (void)hipMemsetAsync(bcnt, 0, (size_t)(NB2 + 1) * 4, stream);
    bhist_kernel<<<NT, 256, 0, stream>>>(edst, bcnt);
    bscan_kernel<<<1, 512, 0, stream>>>(bcnt, bbase, bcur);
    scatter2_kernel<<<NT, 256, 0, stream>>>(esrc, edst, bcur, ebuf);
    csrfill2_kernel<<<NB2, 256, 0, stream>>>(ebuf, bbase, rp, dinv, col);

    // ---- layer 1 (reads fp32 x; fp8 messages; bf16 spine out) ----
    wpre_kernel<<<64, 256, 0, stream>>>(W_in, W_in + 64, 128, wt);
    gemm_mfma_kernel<true, 1><<<gemmGrid, 256, 0, stream>>>(x, wt, dinv, 3, h8);
    agg128_kernel<true><<<aggGrid, 256, 0, stream>>>(h8, x, rp, col, dinv, b_in, xbufw);

    // ---- layer 2 ----
    wpre_kernel<<<64, 256, 0, stream>>>(W_mid0, W_mid0 + 64, 128, wt);
    gemm_mfma_kernel<false, 1><<<gemmGrid, 256, 0, stream>>>(xbuf, wt, dinv, 3, h8);
    agg128_kernel<false><<<aggGrid, 256, 0, stream>>>(h8, xbuf, rp, col, dinv, b_mid0, xbufw);

    // ---- layer 3 ----
    wpre_kernel<<<64, 256, 0, stream>>>(W_mid1, W_mid1 + 64, 128, wt);
    gemm_mfma_kernel<false, 1><<<gemmGrid, 256, 0, stream>>>(xbuf, wt, dinv, 3, h8);
    agg128_kernel<false><<<aggGrid, 256, 0, stream>>>(h8, xbuf, rp, col, dinv, b_mid1, xbufw);

    // ---- layer 4: fused [W_out | W_skip_out] GEMM, split fp8-conv / bf16-skip outputs ----
    wpre_kernel<<<64, 256, 0, stream>>>(W_out, W_skip, 64, wt);
    gemm_mfma_kernel<false, 2><<<gemmGrid, 256, 0, stream>>>(xbuf, wt, dinv, 1, (void*)h8o);
    aggout_kernel<<<aggGrid, 256, 0, stream>>>(h8o, skipb, rp, col, dinv, b_out, outp);
}